// Round 1
// 900.012 us; speedup vs baseline: 1.4032x; 1.4032x over previous
//
#include <hip/hip_runtime.h>

#define Bb 8
#define Nn 1024
#define Cc 768
#define Hh 12
#define Dd 64
#define BHn (Bb*Hh)   // 96
#define Mm (Bb*Nn)    // 8192
#define TCc (3*Cc)    // 2304

typedef __bf16 bf16x8 __attribute__((ext_vector_type(8)));
typedef float  f32x4  __attribute__((ext_vector_type(4)));
typedef __attribute__((address_space(1))) const void* gas_ptr;
typedef __attribute__((address_space(3))) void* las_ptr;

// fragment row/col offsets for the fp32 VALU kernels: t*4+{0..3} and 64+t*4+{0..3}
__device__ __forceinline__ int frag_idx(int t, int r) {
    return (r < 4) ? (t*4 + r) : (64 + t*4 + (r - 4));
}

// ---- fp32 -> bf16 hi/lo split (RNE) ---------------------------------------
__device__ __forceinline__ unsigned short bf16_rne(float f) {
    unsigned int u = __builtin_bit_cast(unsigned int, f);
    u += 0x7fffu + ((u >> 16) & 1u);
    return (unsigned short)(u >> 16);
}
__device__ __forceinline__ void split_bf16(float f, unsigned short& h, unsigned short& l) {
    unsigned short hh = bf16_rne(f);
    float hf = __builtin_bit_cast(float, (unsigned int)hh << 16);
    h = hh;
    l = bf16_rne(f - hf);
}

// ---------------------------------------------------------------------------
// Kernel 0: split fp32 array into bf16 hi / bf16 lo arrays.
// ---------------------------------------------------------------------------
__global__ __launch_bounds__(256)
void split_kernel(const float* __restrict__ src, unsigned short* __restrict__ dh,
                  unsigned short* __restrict__ dl, int n4)
{
    int stride = gridDim.x * blockDim.x;
    for (int i = blockIdx.x * blockDim.x + threadIdx.x; i < n4; i += stride) {
        float4 v = reinterpret_cast<const float4*>(src)[i];
        ushort4 h, l;
        split_bf16(v.x, h.x, l.x);
        split_bf16(v.y, h.y, l.y);
        split_bf16(v.z, h.z, l.z);
        split_bf16(v.w, h.w, l.w);
        reinterpret_cast<ushort4*>(dh)[i] = h;
        reinterpret_cast<ushort4*>(dl)[i] = l;
    }
}

// ---------------------------------------------------------------------------
// bf16x3 NT-GEMM core: C[128x128] = A[M,768] * B[N,768]^T at (m0, j0).
// A,B given as bf16 hi/lo pairs (row-major, K=768 contiguous).
// 256 threads = 4 waves, each wave owns a 64x64 quadrant (4x4 16x16 frags).
// Staging: global_load_lds width-16, linear LDS dest, swizzled global source
// (slot ^= (row>>1)&3) so ds_read_b128 fragment reads are bank-spread.
// 3 MFMAs per fragment pair: hi*hi + hi*lo + lo*hi  (fp32 accumulate).
// ---------------------------------------------------------------------------
__device__ __forceinline__ void gemm128_bf16x3(
    const unsigned short* __restrict__ Agh, const unsigned short* __restrict__ Agl,
    const unsigned short* __restrict__ Bgh, const unsigned short* __restrict__ Bgl,
    int m0, int j0, f32x4 acc[4][4])
{
    __shared__ __align__(16) unsigned short Ash[128*32];
    __shared__ __align__(16) unsigned short Asl[128*32];
    __shared__ __align__(16) unsigned short Bsh[128*32];
    __shared__ __align__(16) unsigned short Bsl[128*32];

    const int tid = threadIdx.x;
    const int ln = tid & 63, wid = tid >> 6;
    const int wr = wid >> 1, wc = wid & 1;

    // one wave stages one full 128x32 tile (8 chunks x 1024B)
    const unsigned short* gsrc =
        (wid == 0) ? Agh + (size_t)m0 * Cc :
        (wid == 1) ? Agl + (size_t)m0 * Cc :
        (wid == 2) ? Bgh + (size_t)j0 * Cc :
                     Bgl + (size_t)j0 * Cc;
    unsigned short* lds = (wid == 0) ? Ash : (wid == 1) ? Asl : (wid == 2) ? Bsh : Bsl;

    const int lrow = ln >> 2, lslot = ln & 3;   // staging: lane -> (row, 16B slot)
    const int r16 = ln & 15,  ko = ln >> 4;     // mfma frag: row, k-block

    f32x4 z = {0.f, 0.f, 0.f, 0.f};
#pragma unroll
    for (int mi = 0; mi < 4; ++mi)
#pragma unroll
        for (int ni = 0; ni < 4; ++ni) acc[mi][ni] = z;

    for (int k0 = 0; k0 < Cc; k0 += 32) {
#pragma unroll
        for (int c = 0; c < 8; ++c) {
            int row = c * 16 + lrow;
            int ss = lslot ^ ((row >> 1) & 3);  // pre-swizzle the SOURCE slot
            const unsigned short* gp = gsrc + (size_t)row * Cc + k0 + ss * 8;
            __builtin_amdgcn_global_load_lds((gas_ptr)gp, (las_ptr)(lds + c * 512), 16u, 0, 0);
        }
        __syncthreads();

        bf16x8 ah[4], al[4], bh[4], bl[4];
#pragma unroll
        for (int mi = 0; mi < 4; ++mi) {
            int row = wr*64 + mi*16 + r16;
            int ss = (ko ^ ((row >> 1) & 3)) * 8;  // same involution on read
            ah[mi] = *reinterpret_cast<const bf16x8*>(Ash + row*32 + ss);
            al[mi] = *reinterpret_cast<const bf16x8*>(Asl + row*32 + ss);
        }
#pragma unroll
        for (int ni = 0; ni < 4; ++ni) {
            int row = wc*64 + ni*16 + r16;
            int ss = (ko ^ ((row >> 1) & 3)) * 8;
            bh[ni] = *reinterpret_cast<const bf16x8*>(Bsh + row*32 + ss);
            bl[ni] = *reinterpret_cast<const bf16x8*>(Bsl + row*32 + ss);
        }
#pragma unroll
        for (int mi = 0; mi < 4; ++mi)
#pragma unroll
            for (int ni = 0; ni < 4; ++ni) {
                acc[mi][ni] = __builtin_amdgcn_mfma_f32_16x16x32_bf16(ah[mi], bh[ni], acc[mi][ni], 0, 0, 0);
                acc[mi][ni] = __builtin_amdgcn_mfma_f32_16x16x32_bf16(ah[mi], bl[ni], acc[mi][ni], 0, 0, 0);
                acc[mi][ni] = __builtin_amdgcn_mfma_f32_16x16x32_bf16(al[mi], bh[ni], acc[mi][ni], 0, 0, 0);
            }
        __syncthreads();
    }
}

// ---------------------------------------------------------------------------
// Kernel 1: QKV projection via bf16x3 MFMA, scatter epilogue to Q/K/V.
// C/D frag layout (16x16x32): col = lane&15, row = (lane>>4)*4 + reg.
// ---------------------------------------------------------------------------
__global__ __launch_bounds__(256, 2)
void qkv_mfma(const unsigned short* __restrict__ xh, const unsigned short* __restrict__ xl,
              const unsigned short* __restrict__ wh, const unsigned short* __restrict__ wl,
              float* __restrict__ Q, float* __restrict__ K, float* __restrict__ V)
{
    const int m0 = blockIdx.x * 128, j0 = blockIdx.y * 128;
    f32x4 acc[4][4];
    gemm128_bf16x3(xh, xl, wh, wl, m0, j0, acc);

    const int tid = threadIdx.x;
    const int ln = tid & 63, wid = tid >> 6;
    const int wr = wid >> 1, wc = wid & 1;
    const int t3 = j0 / Cc;                 // tile never crosses (768 % 128 == 0)
    float* dst = (t3 == 0) ? Q : (t3 == 1) ? K : V;
    const int jr0 = j0 - t3 * Cc;
#pragma unroll
    for (int mi = 0; mi < 4; ++mi) {
        int gm0 = m0 + wr*64 + mi*16 + (ln >> 4) * 4;
#pragma unroll
        for (int ni = 0; ni < 4; ++ni) {
            int col = jr0 + wc*64 + ni*16 + (ln & 15);
            int h = col >> 6, d = col & 63;
#pragma unroll
            for (int i = 0; i < 4; ++i) {
                int gm = gm0 + i;
                int b = gm >> 10, tk = gm & 1023;
                dst[((size_t)((b * Hh + h) * Nn + tk)) * Dd + d] = acc[mi][ni][i];
            }
        }
    }
}

// ---------------------------------------------------------------------------
// Kernel 2: scores (unchanged fp32). E = exp(scale * q.k), rowsums atomically.
// ---------------------------------------------------------------------------
__global__ __launch_bounds__(256)
void scores_kernel(const float* __restrict__ Q, const float* __restrict__ Km,
                   float* __restrict__ E, float* __restrict__ rowsum)
{
    __shared__ float As[16][132];
    __shared__ float Bs[16][132];
    __shared__ float rs[128][17];
    const int tid = threadIdx.x;
    const int tx = tid & 15, ty = tid >> 4;
    const int bh = blockIdx.z;
    const int i0 = blockIdx.x * 128;
    const int j0 = blockIdx.y * 128;
    const float* Qb = Q  + (size_t)bh * Nn * Dd;
    const float* Kb = Km + (size_t)bh * Nn * Dd;
    float*       Eb = E  + (size_t)bh * Nn * Nn;

    float acc[8][8];
#pragma unroll
    for (int i = 0; i < 8; ++i)
#pragma unroll
        for (int j = 0; j < 8; ++j) acc[i][j] = 0.f;

    for (int k0 = 0; k0 < Dd; k0 += 16) {
#pragma unroll
        for (int t = 0; t < 2; ++t) {
            int idx = tid + t * 256;
            int row = idx >> 2, c4 = idx & 3;
            float4 a = *reinterpret_cast<const float4*>(Qb + (size_t)(i0 + row) * Dd + k0 + c4 * 4);
            As[c4*4+0][row] = a.x; As[c4*4+1][row] = a.y;
            As[c4*4+2][row] = a.z; As[c4*4+3][row] = a.w;
            float4 b = *reinterpret_cast<const float4*>(Kb + (size_t)(j0 + row) * Dd + k0 + c4 * 4);
            Bs[c4*4+0][row] = b.x; Bs[c4*4+1][row] = b.y;
            Bs[c4*4+2][row] = b.z; Bs[c4*4+3][row] = b.w;
        }
        __syncthreads();
#pragma unroll
        for (int k = 0; k < 16; ++k) {
            alignas(16) float a[8], b[8];
            *reinterpret_cast<float4*>(&a[0]) = *reinterpret_cast<const float4*>(&As[k][ty*4]);
            *reinterpret_cast<float4*>(&a[4]) = *reinterpret_cast<const float4*>(&As[k][64+ty*4]);
            *reinterpret_cast<float4*>(&b[0]) = *reinterpret_cast<const float4*>(&Bs[k][tx*4]);
            *reinterpret_cast<float4*>(&b[4]) = *reinterpret_cast<const float4*>(&Bs[k][64+tx*4]);
#pragma unroll
            for (int i = 0; i < 8; ++i)
#pragma unroll
                for (int j = 0; j < 8; ++j) acc[i][j] += a[i] * b[j];
        }
        __syncthreads();
    }

    const float scale = 0.125f;
#pragma unroll
    for (int i = 0; i < 8; ++i)
#pragma unroll
        for (int j = 0; j < 8; ++j) acc[i][j] = __expf(acc[i][j] * scale);

#pragma unroll
    for (int ri = 0; ri < 8; ++ri) {
        int row = frag_idx(ty, ri);
        float4 e0 = make_float4(acc[ri][0], acc[ri][1], acc[ri][2], acc[ri][3]);
        float4 e1 = make_float4(acc[ri][4], acc[ri][5], acc[ri][6], acc[ri][7]);
        size_t base = (size_t)(i0 + row) * Nn + j0;
        *reinterpret_cast<float4*>(Eb + base + tx*4)      = e0;
        *reinterpret_cast<float4*>(Eb + base + 64 + tx*4) = e1;
        rs[row][tx] = e0.x + e0.y + e0.z + e0.w + e1.x + e1.y + e1.z + e1.w;
    }
    __syncthreads();
    if (tid < 128) {
        float s = 0.f;
#pragma unroll
        for (int t = 0; t < 16; ++t) s += rs[tid][t];
        atomicAdd(&rowsum[bh * Nn + i0 + tid], s);
    }
}

// ---------------------------------------------------------------------------
// Kernel 3: softmax-normalize E in place + PV GEMM.  O now written as
// bf16 hi/lo pair (consumed by the MFMA proj kernel).
// ---------------------------------------------------------------------------
__global__ __launch_bounds__(256)
void pv_kernel(float* __restrict__ E, const float* __restrict__ V,
               const float* __restrict__ rowsum,
               unsigned short* __restrict__ Oh, unsigned short* __restrict__ Ol)
{
    __shared__ float Ps[32][132];
    __shared__ float Vs[32][68];
    __shared__ float inv_s[128];
    const int tid = threadIdx.x;
    const int tx = tid & 15, ty = tid >> 4;
    const int i0 = blockIdx.x * 128;
    const int bh = blockIdx.y;
    float*       Eb = E + (size_t)bh * Nn * Nn;
    const float* Vb = V + (size_t)bh * Nn * Dd;

    if (tid < 128) inv_s[tid] = 1.0f / rowsum[bh * Nn + i0 + tid];
    __syncthreads();

    float acc[8][4];
#pragma unroll
    for (int i = 0; i < 8; ++i)
#pragma unroll
        for (int j = 0; j < 4; ++j) acc[i][j] = 0.f;

    for (int j0 = 0; j0 < Nn; j0 += 32) {
#pragma unroll
        for (int t = 0; t < 4; ++t) {
            int idx = tid + t * 256;
            int row = idx >> 3, c4 = idx & 7;
            float* gp = Eb + (size_t)(i0 + row) * Nn + j0 + c4 * 4;
            float4 e = *reinterpret_cast<const float4*>(gp);
            float is = inv_s[row];
            float4 p = make_float4(e.x*is, e.y*is, e.z*is, e.w*is);
            *reinterpret_cast<float4*>(gp) = p;
            Ps[c4*4+0][row] = p.x; Ps[c4*4+1][row] = p.y;
            Ps[c4*4+2][row] = p.z; Ps[c4*4+3][row] = p.w;
        }
#pragma unroll
        for (int t = 0; t < 2; ++t) {
            int idx = tid + t * 256;
            int row = idx >> 4, c4 = idx & 15;
            float4 v = *reinterpret_cast<const float4*>(Vb + (size_t)(j0 + row) * Dd + c4 * 4);
            *reinterpret_cast<float4*>(&Vs[row][c4*4]) = v;
        }
        __syncthreads();
#pragma unroll
        for (int k = 0; k < 32; ++k) {
            alignas(16) float a[8];
            *reinterpret_cast<float4*>(&a[0]) = *reinterpret_cast<const float4*>(&Ps[k][ty*4]);
            *reinterpret_cast<float4*>(&a[4]) = *reinterpret_cast<const float4*>(&Ps[k][64+ty*4]);
            float4 b = *reinterpret_cast<const float4*>(&Vs[k][tx*4]);
#pragma unroll
            for (int i = 0; i < 8; ++i) {
                acc[i][0] += a[i] * b.x; acc[i][1] += a[i] * b.y;
                acc[i][2] += a[i] * b.z; acc[i][3] += a[i] * b.w;
            }
        }
        __syncthreads();
    }

    const int b = bh / Hh, h = bh % Hh;
#pragma unroll
    for (int ri = 0; ri < 8; ++ri) {
        int row = frag_idx(ty, ri);
        int n = i0 + row;
        size_t base = ((size_t)(b * Nn + n)) * Cc + h * Dd + tx * 4;
        ushort4 oh, ol;
        split_bf16(acc[ri][0], oh.x, ol.x);
        split_bf16(acc[ri][1], oh.y, ol.y);
        split_bf16(acc[ri][2], oh.z, ol.z);
        split_bf16(acc[ri][3], oh.w, ol.w);
        *reinterpret_cast<ushort4*>(Oh + base) = oh;
        *reinterpret_cast<ushort4*>(Ol + base) = ol;
    }
}

// ---------------------------------------------------------------------------
// Kernel 4: output projection via bf16x3 MFMA + bias.
// ---------------------------------------------------------------------------
__global__ __launch_bounds__(256, 2)
void proj_mfma(const unsigned short* __restrict__ oh, const unsigned short* __restrict__ ol,
               const unsigned short* __restrict__ wh, const unsigned short* __restrict__ wl,
               const float* __restrict__ bias, float* __restrict__ out)
{
    const int m0 = blockIdx.x * 128, j0 = blockIdx.y * 128;
    f32x4 acc[4][4];
    gemm128_bf16x3(oh, ol, wh, wl, m0, j0, acc);

    const int tid = threadIdx.x;
    const int ln = tid & 63, wid = tid >> 6;
    const int wr = wid >> 1, wc = wid & 1;
#pragma unroll
    for (int mi = 0; mi < 4; ++mi) {
        int gm0 = m0 + wr*64 + mi*16 + (ln >> 4) * 4;
#pragma unroll
        for (int ni = 0; ni < 4; ++ni) {
            int col = j0 + wc*64 + ni*16 + (ln & 15);
            float bv = bias[col];
#pragma unroll
            for (int i = 0; i < 4; ++i)
                out[(size_t)(gm0 + i) * Cc + col] = acc[mi][ni][i] + bv;
        }
    }
}

extern "C" void kernel_launch(void* const* d_in, const int* in_sizes, int n_in,
                              void* d_out, int out_size, void* d_ws, size_t ws_size,
                              hipStream_t stream)
{
    const float* x      = (const float*)d_in[0];
    const float* w_qkv  = (const float*)d_in[1];
    const float* w_proj = (const float*)d_in[2];
    const float* b_proj = (const float*)d_in[3];

    float* out  = (float*)d_out;                    // [8192 x 768]
    float* attn = out + (size_t)Mm * Cc;            // [96 x 1024 x 1024]

    const size_t qkv_elems = (size_t)BHn * Nn * Dd; // 6291456
    float* Q      = (float*)d_ws;
    float* K      = Q + qkv_elems;
    float* V      = K + qkv_elems;
    float* Oslot  = V + qkv_elems;                  // holds Oh+Ol bf16 (same bytes as fp32 O)
    float* rowsum = Oslot + (size_t)Mm * Cc;
    unsigned short* wph = (unsigned short*)(rowsum + (size_t)BHn * Nn);
    unsigned short* wpl = wph + (size_t)Cc * Cc;    // only +2.4MB of real ws growth

    unsigned short* Oh = (unsigned short*)Oslot;
    unsigned short* Ol = Oh + (size_t)Mm * Cc;

    // x / w_qkv splits live in the attn output region: dead until scores_kernel
    // overwrites it, and qkv_mfma (the only consumer) completes before that.
    unsigned short* xh  = (unsigned short*)attn;
    unsigned short* xl  = xh + (size_t)Mm * Cc;
    unsigned short* wqh = xl + (size_t)Mm * Cc;
    unsigned short* wql = wqh + (size_t)TCc * Cc;

    hipMemsetAsync(rowsum, 0, (size_t)BHn * Nn * sizeof(float), stream);

    split_kernel<<<dim3(2048), 256, 0, stream>>>(x,      xh,  xl,  (int)((size_t)Mm * Cc / 4));
    split_kernel<<<dim3(1728), 256, 0, stream>>>(w_qkv,  wqh, wql, (int)((size_t)TCc * Cc / 4));
    split_kernel<<<dim3(576),  256, 0, stream>>>(w_proj, wph, wpl, (int)((size_t)Cc * Cc / 4));

    qkv_mfma    <<<dim3(Mm/128, TCc/128), 256, 0, stream>>>(xh, xl, wqh, wql, Q, K, V);
    scores_kernel<<<dim3(Nn/128, Nn/128, BHn), 256, 0, stream>>>(Q, K, attn, rowsum);
    pv_kernel   <<<dim3(Nn/128, BHn), 256, 0, stream>>>(attn, V, rowsum, Oh, Ol);
    proj_mfma   <<<dim3(Mm/128, Cc/128), 256, 0, stream>>>(Oh, Ol, wph, wpl, b_proj, out);
}

// Round 2
// 855.948 us; speedup vs baseline: 1.4754x; 1.0515x over previous
//
#include <hip/hip_runtime.h>

#define Bb 8
#define Nn 1024
#define Cc 768
#define Hh 12
#define Dd 64
#define BHn (Bb*Hh)   // 96
#define Mm (Bb*Nn)    // 8192
#define TCc (3*Cc)    // 2304

typedef __bf16 bf16x8 __attribute__((ext_vector_type(8)));
typedef float  f32x4  __attribute__((ext_vector_type(4)));
typedef __attribute__((address_space(1))) const void* gas_ptr;
typedef __attribute__((address_space(3))) void* las_ptr;
typedef unsigned short u16;

// ---- fp32 -> bf16 hi/lo split (RNE) ---------------------------------------
__device__ __forceinline__ u16 bf16_rne(float f) {
    unsigned int u = __builtin_bit_cast(unsigned int, f);
    u += 0x7fffu + ((u >> 16) & 1u);
    return (u16)(u >> 16);
}
__device__ __forceinline__ void split_bf16(float f, u16& h, u16& l) {
    u16 hh = bf16_rne(f);
    float hf = __builtin_bit_cast(float, (unsigned int)hh << 16);
    h = hh;
    l = bf16_rne(f - hf);
}

// ---------------------------------------------------------------------------
// Kernel 0: split fp32 array into bf16 hi / bf16 lo arrays.
// ---------------------------------------------------------------------------
__global__ __launch_bounds__(256)
void split_kernel(const float* __restrict__ src, u16* __restrict__ dh,
                  u16* __restrict__ dl, int n4)
{
    int stride = gridDim.x * blockDim.x;
    for (int i = blockIdx.x * blockDim.x + threadIdx.x; i < n4; i += stride) {
        float4 v = reinterpret_cast<const float4*>(src)[i];
        ushort4 h, l;
        split_bf16(v.x, h.x, l.x);
        split_bf16(v.y, h.y, l.y);
        split_bf16(v.z, h.z, l.z);
        split_bf16(v.w, h.w, l.w);
        reinterpret_cast<ushort4*>(dh)[i] = h;
        reinterpret_cast<ushort4*>(dl)[i] = l;
    }
}

// ---------------------------------------------------------------------------
// bf16x3 NT-GEMM core (unchanged from round 1): C[128x128] = A * B^T, K=768.
// ---------------------------------------------------------------------------
__device__ __forceinline__ void gemm128_bf16x3(
    const u16* __restrict__ Agh, const u16* __restrict__ Agl,
    const u16* __restrict__ Bgh, const u16* __restrict__ Bgl,
    int m0, int j0, f32x4 acc[4][4])
{
    __shared__ __align__(16) u16 Ash[128*32];
    __shared__ __align__(16) u16 Asl[128*32];
    __shared__ __align__(16) u16 Bsh[128*32];
    __shared__ __align__(16) u16 Bsl[128*32];

    const int tid = threadIdx.x;
    const int ln = tid & 63, wid = tid >> 6;
    const int wr = wid >> 1, wc = wid & 1;

    const u16* gsrc =
        (wid == 0) ? Agh + (size_t)m0 * Cc :
        (wid == 1) ? Agl + (size_t)m0 * Cc :
        (wid == 2) ? Bgh + (size_t)j0 * Cc :
                     Bgl + (size_t)j0 * Cc;
    u16* lds = (wid == 0) ? Ash : (wid == 1) ? Asl : (wid == 2) ? Bsh : Bsl;

    const int lrow = ln >> 2, lslot = ln & 3;
    const int r16 = ln & 15,  ko = ln >> 4;

    f32x4 z = {0.f, 0.f, 0.f, 0.f};
#pragma unroll
    for (int mi = 0; mi < 4; ++mi)
#pragma unroll
        for (int ni = 0; ni < 4; ++ni) acc[mi][ni] = z;

    for (int k0 = 0; k0 < Cc; k0 += 32) {
#pragma unroll
        for (int c = 0; c < 8; ++c) {
            int row = c * 16 + lrow;
            int ss = lslot ^ ((row >> 1) & 3);
            const u16* gp = gsrc + (size_t)row * Cc + k0 + ss * 8;
            __builtin_amdgcn_global_load_lds((gas_ptr)gp, (las_ptr)(lds + c * 512), 16u, 0, 0);
        }
        __syncthreads();

        bf16x8 ah[4], al[4], bh[4], bl[4];
#pragma unroll
        for (int mi = 0; mi < 4; ++mi) {
            int row = wr*64 + mi*16 + r16;
            int ss = (ko ^ ((row >> 1) & 3)) * 8;
            ah[mi] = *reinterpret_cast<const bf16x8*>(Ash + row*32 + ss);
            al[mi] = *reinterpret_cast<const bf16x8*>(Asl + row*32 + ss);
        }
#pragma unroll
        for (int ni = 0; ni < 4; ++ni) {
            int row = wc*64 + ni*16 + r16;
            int ss = (ko ^ ((row >> 1) & 3)) * 8;
            bh[ni] = *reinterpret_cast<const bf16x8*>(Bsh + row*32 + ss);
            bl[ni] = *reinterpret_cast<const bf16x8*>(Bsl + row*32 + ss);
        }
#pragma unroll
        for (int mi = 0; mi < 4; ++mi)
#pragma unroll
            for (int ni = 0; ni < 4; ++ni) {
                acc[mi][ni] = __builtin_amdgcn_mfma_f32_16x16x32_bf16(ah[mi], bh[ni], acc[mi][ni], 0, 0, 0);
                acc[mi][ni] = __builtin_amdgcn_mfma_f32_16x16x32_bf16(ah[mi], bl[ni], acc[mi][ni], 0, 0, 0);
                acc[mi][ni] = __builtin_amdgcn_mfma_f32_16x16x32_bf16(al[mi], bh[ni], acc[mi][ni], 0, 0, 0);
            }
        __syncthreads();
    }
}

// ---------------------------------------------------------------------------
// Kernel 1: QKV projection. Epilogue writes Q,K as bf16 hi/lo [bh][n][d] and
// V TRANSPOSED bf16 hi/lo [bh][d][n] (B-operand layout for the PV MFMA).
// ---------------------------------------------------------------------------
__global__ __launch_bounds__(256, 2)
void qkv_mfma(const u16* __restrict__ xh, const u16* __restrict__ xl,
              const u16* __restrict__ wh, const u16* __restrict__ wl,
              u16* __restrict__ Qh, u16* __restrict__ Ql,
              u16* __restrict__ Kh, u16* __restrict__ Kl,
              u16* __restrict__ Vth, u16* __restrict__ Vtl)
{
    const int m0 = blockIdx.x * 128, j0 = blockIdx.y * 128;
    f32x4 acc[4][4];
    gemm128_bf16x3(xh, xl, wh, wl, m0, j0, acc);

    const int tid = threadIdx.x;
    const int ln = tid & 63, wid = tid >> 6;
    const int wr = wid >> 1, wc = wid & 1;
    const int t3 = j0 / Cc;                 // tile never crosses (768 % 128 == 0)
    const int jr0 = j0 - t3 * Cc;

    if (t3 == 2) {
        // V^T: lane holds 4 consecutive n at fixed d -> ushort4 store
#pragma unroll
        for (int mi = 0; mi < 4; ++mi) {
            int gm0 = m0 + wr*64 + mi*16 + (ln >> 4) * 4;
            int b = gm0 >> 10, n0 = gm0 & 1023;
#pragma unroll
            for (int ni = 0; ni < 4; ++ni) {
                int col = jr0 + wc*64 + ni*16 + (ln & 15);
                int h = col >> 6, d = col & 63;
                u16 hh[4], ll[4];
#pragma unroll
                for (int i = 0; i < 4; ++i) split_bf16(acc[mi][ni][i], hh[i], ll[i]);
                size_t base = ((size_t)((b*Hh + h) * Dd + d)) * Nn + n0;
                *reinterpret_cast<ushort4*>(Vth + base) = make_ushort4(hh[0], hh[1], hh[2], hh[3]);
                *reinterpret_cast<ushort4*>(Vtl + base) = make_ushort4(ll[0], ll[1], ll[2], ll[3]);
            }
        }
    } else {
        u16* dh = (t3 == 0) ? Qh : Kh;
        u16* dl = (t3 == 0) ? Ql : Kl;
#pragma unroll
        for (int mi = 0; mi < 4; ++mi) {
            int gm0 = m0 + wr*64 + mi*16 + (ln >> 4) * 4;
            int b = gm0 >> 10, n0 = gm0 & 1023;
#pragma unroll
            for (int ni = 0; ni < 4; ++ni) {
                int col = jr0 + wc*64 + ni*16 + (ln & 15);
                int h = col >> 6, d = col & 63;
#pragma unroll
                for (int i = 0; i < 4; ++i) {
                    u16 hh, ll;
                    split_bf16(acc[mi][ni][i], hh, ll);
                    size_t base = ((size_t)((b*Hh + h) * Nn + n0 + i)) * Dd + d;
                    dh[base] = hh; dl[base] = ll;
                }
            }
        }
    }
}

// ---------------------------------------------------------------------------
// Kernel 2: scores via bf16x3 MFMA. Whole K=64 staged once (64 KiB LDS,
// one wave per array). E = exp(scale*S) written unnormalized; rowsum via
// shfl_xor column-reduce + one global atomicAdd per lane.
// LDS swizzle: 128B rows of 8x16B slots, slot ^= row&7 (both sides).
// ---------------------------------------------------------------------------
__global__ __launch_bounds__(256, 2)
void scores_mfma(const u16* __restrict__ Qh_, const u16* __restrict__ Ql_,
                 const u16* __restrict__ Kh_, const u16* __restrict__ Kl_,
                 float* __restrict__ E, float* __restrict__ rowsum)
{
    __shared__ __align__(16) u16 sQh[128*64];
    __shared__ __align__(16) u16 sQl[128*64];
    __shared__ __align__(16) u16 sKh[128*64];
    __shared__ __align__(16) u16 sKl[128*64];

    const int tid = threadIdx.x;
    const int ln = tid & 63, wid = tid >> 6;
    const int wr = wid >> 1, wc = wid & 1;
    const int bh = blockIdx.z;
    const int i0 = blockIdx.x * 128, j0 = blockIdx.y * 128;
    const int r16 = ln & 15, ko = ln >> 4;

    {   // stage: each wave stages one 128x64 bf16 array (16 chunks x 1024B)
        const u16* gsrc =
            (wid == 0) ? Qh_ + (size_t)(bh*Nn + i0) * Dd :
            (wid == 1) ? Ql_ + (size_t)(bh*Nn + i0) * Dd :
            (wid == 2) ? Kh_ + (size_t)(bh*Nn + j0) * Dd :
                         Kl_ + (size_t)(bh*Nn + j0) * Dd;
        u16* lds = (wid == 0) ? sQh : (wid == 1) ? sQl : (wid == 2) ? sKh : sKl;
        int r = ln >> 3, s = ln & 7;
        int ss = s ^ (r & 7);                       // pre-swizzle SOURCE slot
        const u16* gp = gsrc + r*64 + ss*8;
#pragma unroll
        for (int c = 0; c < 16; ++c)
            __builtin_amdgcn_global_load_lds((gas_ptr)(gp + c*512), (las_ptr)(lds + c*512), 16u, 0, 0);
    }
    __syncthreads();

    f32x4 acc[4][4];
    f32x4 z = {0.f, 0.f, 0.f, 0.f};
#pragma unroll
    for (int mi = 0; mi < 4; ++mi)
#pragma unroll
        for (int ni = 0; ni < 4; ++ni) acc[mi][ni] = z;

#pragma unroll
    for (int kk = 0; kk < 2; ++kk) {
        bf16x8 qh[4], ql[4], kh[4], kl[4];
#pragma unroll
        for (int mi = 0; mi < 4; ++mi) {
            int row = wr*64 + mi*16 + r16;
            int s = (kk*4 + ko) ^ (row & 7);
            qh[mi] = *reinterpret_cast<const bf16x8*>(sQh + row*64 + s*8);
            ql[mi] = *reinterpret_cast<const bf16x8*>(sQl + row*64 + s*8);
        }
#pragma unroll
        for (int ni = 0; ni < 4; ++ni) {
            int row = wc*64 + ni*16 + r16;
            int s = (kk*4 + ko) ^ (row & 7);
            kh[ni] = *reinterpret_cast<const bf16x8*>(sKh + row*64 + s*8);
            kl[ni] = *reinterpret_cast<const bf16x8*>(sKl + row*64 + s*8);
        }
#pragma unroll
        for (int mi = 0; mi < 4; ++mi)
#pragma unroll
            for (int ni = 0; ni < 4; ++ni) {
                acc[mi][ni] = __builtin_amdgcn_mfma_f32_16x16x32_bf16(qh[mi], kh[ni], acc[mi][ni], 0, 0, 0);
                acc[mi][ni] = __builtin_amdgcn_mfma_f32_16x16x32_bf16(qh[mi], kl[ni], acc[mi][ni], 0, 0, 0);
                acc[mi][ni] = __builtin_amdgcn_mfma_f32_16x16x32_bf16(ql[mi], kh[ni], acc[mi][ni], 0, 0, 0);
            }
    }

    // epilogue: exp, write E (16-lane x 4B = 64B coalesced), row sums
    const float scale = 0.125f;
    float* Eb = E + (size_t)bh * Nn * Nn;
    float vsum[4][4];
#pragma unroll
    for (int mi = 0; mi < 4; ++mi)
#pragma unroll
        for (int i = 0; i < 4; ++i) vsum[mi][i] = 0.f;

#pragma unroll
    for (int mi = 0; mi < 4; ++mi) {
        int row = i0 + wr*64 + mi*16 + ko*4;
#pragma unroll
        for (int ni = 0; ni < 4; ++ni) {
            int col = j0 + wc*64 + ni*16 + r16;
#pragma unroll
            for (int i = 0; i < 4; ++i) {
                float v = __expf(acc[mi][ni][i] * scale);
                vsum[mi][i] += v;
                Eb[(size_t)(row + i) * Nn + col] = v;
            }
        }
    }
    // reduce over the 16 column-lanes (bits 0-3 of lane id)
#pragma unroll
    for (int mi = 0; mi < 4; ++mi)
#pragma unroll
        for (int i = 0; i < 4; ++i) {
            float v = vsum[mi][i];
            v += __shfl_xor(v, 1); v += __shfl_xor(v, 2);
            v += __shfl_xor(v, 4); v += __shfl_xor(v, 8);
            vsum[mi][i] = v;
        }
    {   // one atomic per lane: (mi,i) chosen by r16, row includes own ko
        int mi = r16 >> 2, i = r16 & 3;
        int row = i0 + wr*64 + mi*16 + ko*4 + i;
        atomicAdd(&rowsum[bh * Nn + row], vsum[mi][i]);
    }
}

// ---------------------------------------------------------------------------
// Kernel 3: PV via bf16x3 MFMA. Per (bh,i0): loop j in 64-chunks; load E
// (float4), normalize, write final attn back, split P->bf16 pair into
// swizzled LDS; Vt staged by global_load_lds; O written as bf16 pair.
// ---------------------------------------------------------------------------
__global__ __launch_bounds__(256, 2)
void pv_mfma(float* __restrict__ E, const u16* __restrict__ Vth, const u16* __restrict__ Vtl,
             const float* __restrict__ rowsum,
             u16* __restrict__ Oh, u16* __restrict__ Ol)
{
    __shared__ __align__(16) u16 sPh[128*64];
    __shared__ __align__(16) u16 sPl[128*64];
    __shared__ __align__(16) u16 sVh[64*64];
    __shared__ __align__(16) u16 sVl[64*64];
    __shared__ float inv_s[128];

    const int tid = threadIdx.x;
    const int ln = tid & 63, wid = tid >> 6;
    const int i0 = blockIdx.x * 128;
    const int bh = blockIdx.y;
    const int r16 = ln & 15, ko = ln >> 4;
    float* Eb = E + (size_t)bh * Nn * Nn;

    if (tid < 128) inv_s[tid] = 1.0f / rowsum[bh * Nn + i0 + tid];
    __syncthreads();

    f32x4 acc[2][4];
    f32x4 z = {0.f, 0.f, 0.f, 0.f};
#pragma unroll
    for (int mi = 0; mi < 2; ++mi)
#pragma unroll
        for (int ni = 0; ni < 4; ++ni) acc[mi][ni] = z;

    for (int j0 = 0; j0 < Nn; j0 += 64) {
        // stage Vt tile [64 d][64 j] hi/lo via global_load_lds (waves 0,1)
        if (wid < 2) {
            const u16* gsrc = ((wid == 0) ? Vth : Vtl) + (size_t)bh * Dd * Nn + j0;
            u16* lds = (wid == 0) ? sVh : sVl;
            int r = ln >> 3, s = ln & 7;
            int ss = s ^ (r & 7);
            const u16* gp = gsrc + (size_t)r * Nn + ss*8;
#pragma unroll
            for (int c = 0; c < 8; ++c)
                __builtin_amdgcn_global_load_lds((gas_ptr)(gp + (size_t)c*8*Nn), (las_ptr)(lds + c*512), 16u, 0, 0);
        }
        // stage P: load E, normalize, write attn back, split to LDS pair
#pragma unroll
        for (int it = 0; it < 8; ++it) {
            int idx = tid + it * 256;
            int row = idx >> 4, c4 = idx & 15;
            float* gp = Eb + (size_t)(i0 + row) * Nn + j0 + c4*4;
            float4 e = *reinterpret_cast<const float4*>(gp);
            float is = inv_s[row];
            float4 p = make_float4(e.x*is, e.y*is, e.z*is, e.w*is);
            *reinterpret_cast<float4*>(gp) = p;           // final attn value
            u16 h[4], l[4];
            split_bf16(p.x, h[0], l[0]); split_bf16(p.y, h[1], l[1]);
            split_bf16(p.z, h[2], l[2]); split_bf16(p.w, h[3], l[3]);
            int s = (c4 >> 1) ^ (row & 7);
            int off = row*64 + s*8 + (c4 & 1)*4;
            *reinterpret_cast<ushort4*>(sPh + off) = make_ushort4(h[0], h[1], h[2], h[3]);
            *reinterpret_cast<ushort4*>(sPl + off) = make_ushort4(l[0], l[1], l[2], l[3]);
        }
        __syncthreads();

#pragma unroll
        for (int kk = 0; kk < 2; ++kk) {
            bf16x8 ph[2], pl[2], vh[4], vl[4];
#pragma unroll
            for (int mi = 0; mi < 2; ++mi) {
                int row = wid*32 + mi*16 + r16;
                int s = (kk*4 + ko) ^ (row & 7);
                ph[mi] = *reinterpret_cast<const bf16x8*>(sPh + row*64 + s*8);
                pl[mi] = *reinterpret_cast<const bf16x8*>(sPl + row*64 + s*8);
            }
#pragma unroll
            for (int ni = 0; ni < 4; ++ni) {
                int row = ni*16 + r16;
                int s = (kk*4 + ko) ^ (row & 7);
                vh[ni] = *reinterpret_cast<const bf16x8*>(sVh + row*64 + s*8);
                vl[ni] = *reinterpret_cast<const bf16x8*>(sVl + row*64 + s*8);
            }
#pragma unroll
            for (int mi = 0; mi < 2; ++mi)
#pragma unroll
                for (int ni = 0; ni < 4; ++ni) {
                    acc[mi][ni] = __builtin_amdgcn_mfma_f32_16x16x32_bf16(ph[mi], vh[ni], acc[mi][ni], 0, 0, 0);
                    acc[mi][ni] = __builtin_amdgcn_mfma_f32_16x16x32_bf16(ph[mi], vl[ni], acc[mi][ni], 0, 0, 0);
                    acc[mi][ni] = __builtin_amdgcn_mfma_f32_16x16x32_bf16(pl[mi], vh[ni], acc[mi][ni], 0, 0, 0);
                }
        }
        __syncthreads();
    }

    const int b = bh / Hh, h = bh % Hh;
#pragma unroll
    for (int mi = 0; mi < 2; ++mi) {
        int n0 = i0 + wid*32 + mi*16 + ko*4;
#pragma unroll
        for (int ni = 0; ni < 4; ++ni) {
            int d = ni*16 + r16;
#pragma unroll
            for (int i = 0; i < 4; ++i) {
                u16 hh, ll;
                split_bf16(acc[mi][ni][i], hh, ll);
                size_t base = ((size_t)(b * Nn + n0 + i)) * Cc + h * Dd + d;
                Oh[base] = hh; Ol[base] = ll;
            }
        }
    }
}

// ---------------------------------------------------------------------------
// Kernel 4: output projection via bf16x3 MFMA + bias (unchanged).
// ---------------------------------------------------------------------------
__global__ __launch_bounds__(256, 2)
void proj_mfma(const u16* __restrict__ oh, const u16* __restrict__ ol,
               const u16* __restrict__ wh, const u16* __restrict__ wl,
               const float* __restrict__ bias, float* __restrict__ out)
{
    const int m0 = blockIdx.x * 128, j0 = blockIdx.y * 128;
    f32x4 acc[4][4];
    gemm128_bf16x3(oh, ol, wh, wl, m0, j0, acc);

    const int tid = threadIdx.x;
    const int ln = tid & 63, wid = tid >> 6;
    const int wr = wid >> 1, wc = wid & 1;
#pragma unroll
    for (int mi = 0; mi < 4; ++mi) {
        int gm0 = m0 + wr*64 + mi*16 + (ln >> 4) * 4;
#pragma unroll
        for (int ni = 0; ni < 4; ++ni) {
            int col = j0 + wc*64 + ni*16 + (ln & 15);
            float bv = bias[col];
#pragma unroll
            for (int i = 0; i < 4; ++i)
                out[(size_t)(gm0 + i) * Cc + col] = acc[mi][ni][i] + bv;
        }
    }
}

extern "C" void kernel_launch(void* const* d_in, const int* in_sizes, int n_in,
                              void* d_out, int out_size, void* d_ws, size_t ws_size,
                              hipStream_t stream)
{
    const float* x      = (const float*)d_in[0];
    const float* w_qkv  = (const float*)d_in[1];
    const float* w_proj = (const float*)d_in[2];
    const float* b_proj = (const float*)d_in[3];

    float* out  = (float*)d_out;                    // [8192 x 768]
    float* attn = out + (size_t)Mm * Cc;            // [96 x 1024 x 1024]

    const size_t qkv_elems = (size_t)BHn * Nn * Dd; // 6291456
    // bf16 hi/lo pairs for Q,K ([bh][n][d]) and V^T ([bh][d][n]) — same total
    // bytes as the old fp32 Q,K,V.
    u16* Qh  = (u16*)d_ws;
    u16* Ql  = Qh  + qkv_elems;
    u16* Kh  = Ql  + qkv_elems;
    u16* Kl  = Kh  + qkv_elems;
    u16* Vth = Kl  + qkv_elems;
    u16* Vtl = Vth + qkv_elems;
    float* Oslot  = (float*)(Vtl + qkv_elems);      // Oh+Ol bf16 = Mm*Cc fp32 bytes
    float* rowsum = Oslot + (size_t)Mm * Cc;
    u16* wph = (u16*)(rowsum + (size_t)BHn * Nn);
    u16* wpl = wph + (size_t)Cc * Cc;

    u16* Oh = (u16*)Oslot;
    u16* Ol = Oh + (size_t)Mm * Cc;

    // x / w_qkv splits live in the attn output region: dead until scores_mfma
    // overwrites it, and qkv_mfma (the only consumer) completes before that.
    u16* xh  = (u16*)attn;
    u16* xl  = xh + (size_t)Mm * Cc;
    u16* wqh = xl + (size_t)Mm * Cc;
    u16* wql = wqh + (size_t)TCc * Cc;

    hipMemsetAsync(rowsum, 0, (size_t)BHn * Nn * sizeof(float), stream);

    split_kernel<<<dim3(2048), 256, 0, stream>>>(x,      xh,  xl,  (int)((size_t)Mm * Cc / 4));
    split_kernel<<<dim3(1728), 256, 0, stream>>>(w_qkv,  wqh, wql, (int)((size_t)TCc * Cc / 4));
    split_kernel<<<dim3(576),  256, 0, stream>>>(w_proj, wph, wpl, (int)((size_t)Cc * Cc / 4));

    qkv_mfma   <<<dim3(Mm/128, TCc/128), 256, 0, stream>>>(xh, xl, wqh, wql,
                                                           Qh, Ql, Kh, Kl, Vth, Vtl);
    scores_mfma<<<dim3(Nn/128, Nn/128, BHn), 256, 0, stream>>>(Qh, Ql, Kh, Kl, attn, rowsum);
    pv_mfma    <<<dim3(Nn/128, BHn), 256, 0, stream>>>(attn, Vth, Vtl, rowsum, Oh, Ol);
    proj_mfma  <<<dim3(Mm/128, Cc/128), 256, 0, stream>>>(Oh, Ol, wph, wpl, b_proj, out);
}

// Round 3
// 708.661 us; speedup vs baseline: 1.7820x; 1.2078x over previous
//
#include <hip/hip_runtime.h>

#define Bb 8
#define Nn 1024
#define Cc 768
#define Hh 12
#define Dd 64
#define BHn (Bb*Hh)   // 96
#define Mm (Bb*Nn)    // 8192
#define TCc (3*Cc)    // 2304

typedef __bf16 bf16x8 __attribute__((ext_vector_type(8)));
typedef float  f32x4  __attribute__((ext_vector_type(4)));
typedef __attribute__((address_space(1))) const void* gas_ptr;
typedef __attribute__((address_space(3))) void* las_ptr;
typedef unsigned short u16;

// ---- fp32 -> bf16 hi/lo split (RNE) ---------------------------------------
__device__ __forceinline__ u16 bf16_rne(float f) {
    unsigned int u = __builtin_bit_cast(unsigned int, f);
    u += 0x7fffu + ((u >> 16) & 1u);
    return (u16)(u >> 16);
}
__device__ __forceinline__ void split_bf16(float f, u16& h, u16& l) {
    u16 hh = bf16_rne(f);
    float hf = __builtin_bit_cast(float, (unsigned int)hh << 16);
    h = hh;
    l = bf16_rne(f - hf);
}

// Q/K tile-image: per (bh, n-tile of 128) a 128x64 u16 block whose element
// (row,d) sits at row*64 + ((d>>3)^(row&7))*8 + (d&7)  — i.e. the LDS image
// (slot-swizzled) that the MFMA frag reads expect. Consumers stage LINEARLY.
__device__ __forceinline__ int img_off(int row, int d) {
    return row*64 + (((d >> 3) ^ (row & 7)) << 3) + (d & 7);
}

// ---------------------------------------------------------------------------
// Kernel 0: split fp32 array into bf16 hi / bf16 lo arrays.
// ---------------------------------------------------------------------------
__global__ __launch_bounds__(256)
void split_kernel(const float* __restrict__ src, u16* __restrict__ dh,
                  u16* __restrict__ dl, int n4)
{
    int stride = gridDim.x * blockDim.x;
    for (int i = blockIdx.x * blockDim.x + threadIdx.x; i < n4; i += stride) {
        float4 v = reinterpret_cast<const float4*>(src)[i];
        ushort4 h, l;
        split_bf16(v.x, h.x, l.x);
        split_bf16(v.y, h.y, l.y);
        split_bf16(v.z, h.z, l.z);
        split_bf16(v.w, h.w, l.w);
        reinterpret_cast<ushort4*>(dh)[i] = h;
        reinterpret_cast<ushort4*>(dl)[i] = l;
    }
}

// ---------------------------------------------------------------------------
// bf16x3 NT-GEMM core: C[128x128] = A * B^T, K=768 (unchanged, verified).
// ---------------------------------------------------------------------------
__device__ __forceinline__ void gemm128_bf16x3(
    const u16* __restrict__ Agh, const u16* __restrict__ Agl,
    const u16* __restrict__ Bgh, const u16* __restrict__ Bgl,
    int m0, int j0, f32x4 acc[4][4])
{
    __shared__ __align__(16) u16 Ash[128*32];
    __shared__ __align__(16) u16 Asl[128*32];
    __shared__ __align__(16) u16 Bsh[128*32];
    __shared__ __align__(16) u16 Bsl[128*32];

    const int tid = threadIdx.x;
    const int ln = tid & 63, wid = tid >> 6;
    const int wr = wid >> 1, wc = wid & 1;

    const u16* gsrc =
        (wid == 0) ? Agh + (size_t)m0 * Cc :
        (wid == 1) ? Agl + (size_t)m0 * Cc :
        (wid == 2) ? Bgh + (size_t)j0 * Cc :
                     Bgl + (size_t)j0 * Cc;
    u16* lds = (wid == 0) ? Ash : (wid == 1) ? Asl : (wid == 2) ? Bsh : Bsl;

    const int lrow = ln >> 2, lslot = ln & 3;
    const int r16 = ln & 15,  ko = ln >> 4;

    f32x4 z = {0.f, 0.f, 0.f, 0.f};
#pragma unroll
    for (int mi = 0; mi < 4; ++mi)
#pragma unroll
        for (int ni = 0; ni < 4; ++ni) acc[mi][ni] = z;

    for (int k0 = 0; k0 < Cc; k0 += 32) {
#pragma unroll
        for (int c = 0; c < 8; ++c) {
            int row = c * 16 + lrow;
            int ss = lslot ^ ((row >> 1) & 3);
            const u16* gp = gsrc + (size_t)row * Cc + k0 + ss * 8;
            __builtin_amdgcn_global_load_lds((gas_ptr)gp, (las_ptr)(lds + c * 512), 16u, 0, 0);
        }
        __syncthreads();

        bf16x8 ah[4], al[4], bh[4], bl[4];
#pragma unroll
        for (int mi = 0; mi < 4; ++mi) {
            int row = wr*64 + mi*16 + r16;
            int ss = (ko ^ ((row >> 1) & 3)) * 8;
            ah[mi] = *reinterpret_cast<const bf16x8*>(Ash + row*32 + ss);
            al[mi] = *reinterpret_cast<const bf16x8*>(Asl + row*32 + ss);
        }
#pragma unroll
        for (int ni = 0; ni < 4; ++ni) {
            int row = wc*64 + ni*16 + r16;
            int ss = (ko ^ ((row >> 1) & 3)) * 8;
            bh[ni] = *reinterpret_cast<const bf16x8*>(Bsh + row*32 + ss);
            bl[ni] = *reinterpret_cast<const bf16x8*>(Bsl + row*32 + ss);
        }
#pragma unroll
        for (int mi = 0; mi < 4; ++mi)
#pragma unroll
            for (int ni = 0; ni < 4; ++ni) {
                acc[mi][ni] = __builtin_amdgcn_mfma_f32_16x16x32_bf16(ah[mi], bh[ni], acc[mi][ni], 0, 0, 0);
                acc[mi][ni] = __builtin_amdgcn_mfma_f32_16x16x32_bf16(ah[mi], bl[ni], acc[mi][ni], 0, 0, 0);
                acc[mi][ni] = __builtin_amdgcn_mfma_f32_16x16x32_bf16(al[mi], bh[ni], acc[mi][ni], 0, 0, 0);
            }
        __syncthreads();
    }
}

// ---------------------------------------------------------------------------
// Kernel 1: QKV projection. Q/K written as swizzled tile-images (via LDS
// repack -> coalesced uint4 stores); V written transposed [bh][d][n] (as r2).
// ---------------------------------------------------------------------------
__global__ __launch_bounds__(256, 2)
void qkv_mfma(const u16* __restrict__ xh, const u16* __restrict__ xl,
              const u16* __restrict__ wh, const u16* __restrict__ wl,
              u16* __restrict__ Qh, u16* __restrict__ Ql,
              u16* __restrict__ Kh, u16* __restrict__ Kl,
              u16* __restrict__ Vth, u16* __restrict__ Vtl)
{
    __shared__ __align__(16) u16 Rs[16384];   // 2-head repack buffer (32 KiB)
    const int m0 = blockIdx.x * 128, j0 = blockIdx.y * 128;
    f32x4 acc[4][4];
    gemm128_bf16x3(xh, xl, wh, wl, m0, j0, acc);

    const int tid = threadIdx.x;
    const int ln = tid & 63, wid = tid >> 6;
    const int wr = wid >> 1, wc = wid & 1;
    const int r16 = ln & 15, ko = ln >> 4;
    const int t3 = j0 / Cc;                 // tile never crosses (768 % 128 == 0)
    const int jr0 = j0 - t3 * Cc;
    const int b = m0 >> 10, nt = (m0 >> 7) & 7;
    const int h1 = jr0 >> 6;

    if (t3 == 2) {
        // V^T: lane holds 4 consecutive n at fixed d -> ushort4 store
#pragma unroll
        for (int mi = 0; mi < 4; ++mi) {
            int gm0 = m0 + wr*64 + mi*16 + ko*4;
            int n0 = gm0 & 1023;
#pragma unroll
            for (int ni = 0; ni < 4; ++ni) {
                int col = jr0 + wc*64 + ni*16 + r16;
                int h = col >> 6, d = col & 63;
                u16 hh[4], ll[4];
#pragma unroll
                for (int i = 0; i < 4; ++i) split_bf16(acc[mi][ni][i], hh[i], ll[i]);
                size_t base = ((size_t)((b*Hh + h) * Dd + d)) * Nn + n0;
                *reinterpret_cast<ushort4*>(Vth + base) = make_ushort4(hh[0], hh[1], hh[2], hh[3]);
                *reinterpret_cast<ushort4*>(Vtl + base) = make_ushort4(ll[0], ll[1], ll[2], ll[3]);
            }
        }
    } else {
        u16* dh = (t3 == 0) ? Qh : Kh;
        u16* dl = (t3 == 0) ? Ql : Kl;
#pragma unroll
        for (int pass = 0; pass < 2; ++pass) {
#pragma unroll
            for (int mi = 0; mi < 4; ++mi)
#pragma unroll
                for (int ni = 0; ni < 4; ++ni)
#pragma unroll
                    for (int i = 0; i < 4; ++i) {
                        int row = wr*64 + mi*16 + ko*4 + i;
                        int col = wc*64 + ni*16 + r16;
                        float v = acc[mi][ni][i];
                        u16 hh = bf16_rne(v);
                        u16 val = hh;
                        if (pass) {
                            float hf = __builtin_bit_cast(float, (unsigned int)hh << 16);
                            val = bf16_rne(v - hf);
                        }
                        Rs[(col >> 6) * 8192 + img_off(row, col & 63)] = val;
                    }
            __syncthreads();
            u16* gout = pass ? dl : dh;
#pragma unroll
            for (int it = 0; it < 8; ++it) {
                int off = (it * 256 + tid) * 8;      // u16 index, 16B aligned
                int hd = off >> 13, w16 = off & 8191;
                u16* gp = gout + ((size_t)((b*Hh + h1 + hd) * 8 + nt)) * 8192 + w16;
                *reinterpret_cast<uint4*>(gp) = *reinterpret_cast<const uint4*>(&Rs[off]);
            }
            __syncthreads();
        }
    }
}

// ---------------------------------------------------------------------------
// Kernel 2: fused attention. Per (bh, 128 Q-rows): pass 1 computes row sums
// (QK^T MFMA + exp, wave-local shfl reduce — no atomics); pass 2 recomputes
// S (bitwise-identical MFMA order), normalizes, writes attn ONCE, splits P
// to bf16 pair in LDS, and accumulates PV. E never round-trips HBM.
// ---------------------------------------------------------------------------
__global__ __launch_bounds__(256, 2)
void attn_fused(const u16* __restrict__ Qh_, const u16* __restrict__ Ql_,
                const u16* __restrict__ Kh_, const u16* __restrict__ Kl_,
                const u16* __restrict__ Vth, const u16* __restrict__ Vtl,
                float* __restrict__ E, u16* __restrict__ Oh, u16* __restrict__ Ol)
{
    __shared__ __align__(16) u16 pool[32768];   // 64 KiB
    u16* sKh = pool;                // 4096 (64x64)
    u16* sKl = pool + 4096;
    u16* sVh = pool + 8192;         // 4096 (64 d x 64 j)
    u16* sVl = pool + 12288;
    u16* sPh = pool + 16384;        // 8192 (128x64); aliases Q stage
    u16* sPl = pool + 24576;
    u16* sQh = pool + 16384;
    u16* sQl = pool + 24576;

    const int tid = threadIdx.x;
    const int ln = tid & 63, w = tid >> 6;
    const int r16 = ln & 15, ko = ln >> 4;

    // XCD swizzle: 8 consecutive-dispatch blocks (one per XCD) -> contiguous
    // swz chunks, so all 8 i-blocks of one bh share an XCD's L2 K/V.
    const int lid = blockIdx.x;                  // 0..767
    const int swz = (lid & 7) * 96 + (lid >> 3);
    const int i0 = (swz & 7) * 128;
    const int bh = swz >> 3;

    // ---- stage Q tile-image pair (linear copy; swizzle baked in) ----
    {
        const size_t qbase = ((size_t)bh * 8 + (i0 >> 7)) * 8192;
        const u16* src = ((w < 2) ? Qh_ : Ql_) + qbase;
        u16* dst = (w < 2) ? sQh : sQl;
        int cbase = (w & 1) * 8;
#pragma unroll
        for (int c = 0; c < 8; ++c)
            __builtin_amdgcn_global_load_lds((gas_ptr)(src + (cbase + c) * 512 + ln * 8),
                                             (las_ptr)(dst + (cbase + c) * 512), 16u, 0, 0);
    }
    __syncthreads();
    bf16x8 qh[2][2], ql[2][2];
#pragma unroll
    for (int mi = 0; mi < 2; ++mi) {
        int row = w*32 + mi*16 + r16;
#pragma unroll
        for (int kk = 0; kk < 2; ++kk) {
            int idx = row*64 + ((kk*4 + ko) ^ (row & 7)) * 8;
            qh[mi][kk] = *reinterpret_cast<const bf16x8*>(sQh + idx);
            ql[mi][kk] = *reinterpret_cast<const bf16x8*>(sQl + idx);
        }
    }
    __syncthreads();   // Q region becomes P region

    const float scale = 0.125f;
    const f32x4 z = {0.f, 0.f, 0.f, 0.f};

    // ---- pass 1: row sums ----
    float vsum[2][4];
#pragma unroll
    for (int mi = 0; mi < 2; ++mi)
#pragma unroll
        for (int i = 0; i < 4; ++i) vsum[mi][i] = 0.f;

    for (int j0 = 0; j0 < Nn; j0 += 64) {
        const size_t kbase = ((size_t)bh * 8 + (j0 >> 7)) * 8192 + ((j0 >> 6) & 1) * 4096;
        {   // waves 0,1 -> Kh ; waves 2,3 -> Kl (4 chunks each)
            const u16* src = ((w >> 1) ? Kl_ : Kh_) + kbase;
            u16* dst = (w >> 1) ? sKl : sKh;
            int cbase = (w & 1) * 4;
#pragma unroll
            for (int c = 0; c < 4; ++c)
                __builtin_amdgcn_global_load_lds((gas_ptr)(src + (cbase + c) * 512 + ln * 8),
                                                 (las_ptr)(dst + (cbase + c) * 512), 16u, 0, 0);
        }
        __syncthreads();

        f32x4 acc[2][4];
#pragma unroll
        for (int mi = 0; mi < 2; ++mi)
#pragma unroll
            for (int ni = 0; ni < 4; ++ni) acc[mi][ni] = z;
#pragma unroll
        for (int kk = 0; kk < 2; ++kk) {
            bf16x8 kh[4], kl[4];
#pragma unroll
            for (int ni = 0; ni < 4; ++ni) {
                int row = ni*16 + r16;
                int idx = row*64 + ((kk*4 + ko) ^ (row & 7)) * 8;
                kh[ni] = *reinterpret_cast<const bf16x8*>(sKh + idx);
                kl[ni] = *reinterpret_cast<const bf16x8*>(sKl + idx);
            }
#pragma unroll
            for (int mi = 0; mi < 2; ++mi)
#pragma unroll
                for (int ni = 0; ni < 4; ++ni) {
                    acc[mi][ni] = __builtin_amdgcn_mfma_f32_16x16x32_bf16(qh[mi][kk], kh[ni], acc[mi][ni], 0, 0, 0);
                    acc[mi][ni] = __builtin_amdgcn_mfma_f32_16x16x32_bf16(qh[mi][kk], kl[ni], acc[mi][ni], 0, 0, 0);
                    acc[mi][ni] = __builtin_amdgcn_mfma_f32_16x16x32_bf16(ql[mi][kk], kh[ni], acc[mi][ni], 0, 0, 0);
                }
        }
        __syncthreads();   // K reads done before restage
#pragma unroll
        for (int mi = 0; mi < 2; ++mi)
#pragma unroll
            for (int ni = 0; ni < 4; ++ni)
#pragma unroll
                for (int i = 0; i < 4; ++i)
                    vsum[mi][i] += __expf(acc[mi][ni][i] * scale);
    }

    // wave-local row-sum reduce (each wave owns its 32 rows)
    float inv[2][4];
#pragma unroll
    for (int mi = 0; mi < 2; ++mi)
#pragma unroll
        for (int i = 0; i < 4; ++i) {
            float v = vsum[mi][i];
            v += __shfl_xor(v, 1); v += __shfl_xor(v, 2);
            v += __shfl_xor(v, 4); v += __shfl_xor(v, 8);
            inv[mi][i] = 1.0f / v;
        }

    // ---- pass 2: recompute S, normalize, write attn, PV ----
    f32x4 oacc[2][4];
#pragma unroll
    for (int mi = 0; mi < 2; ++mi)
#pragma unroll
        for (int ni = 0; ni < 4; ++ni) oacc[mi][ni] = z;
    float* Eb = E + (size_t)bh * Nn * Nn;

    for (int j0 = 0; j0 < Nn; j0 += 64) {
        const size_t kbase = ((size_t)bh * 8 + (j0 >> 7)) * 8192 + ((j0 >> 6) & 1) * 4096;
        if (w < 2) {        // K pair, 8 chunks per wave
            const u16* src = (w ? Kl_ : Kh_) + kbase;
            u16* dst = w ? sKl : sKh;
#pragma unroll
            for (int c = 0; c < 8; ++c)
                __builtin_amdgcn_global_load_lds((gas_ptr)(src + c * 512 + ln * 8),
                                                 (las_ptr)(dst + c * 512), 16u, 0, 0);
        } else {            // V pair from Vt[bh][d][n], swizzled source
            const u16* src0 = ((w == 2) ? Vth : Vtl) + (size_t)bh * Dd * Nn + j0;
            u16* dst = (w == 2) ? sVh : sVl;
            int r = ln >> 3, s = ln & 7, ss = s ^ (r & 7);
            const u16* gp = src0 + (size_t)r * Nn + ss * 8;
#pragma unroll
            for (int c = 0; c < 8; ++c)
                __builtin_amdgcn_global_load_lds((gas_ptr)(gp + (size_t)c * 8 * Nn),
                                                 (las_ptr)(dst + c * 512), 16u, 0, 0);
        }
        __syncthreads();

        f32x4 acc[2][4];
#pragma unroll
        for (int mi = 0; mi < 2; ++mi)
#pragma unroll
            for (int ni = 0; ni < 4; ++ni) acc[mi][ni] = z;
#pragma unroll
        for (int kk = 0; kk < 2; ++kk) {
            bf16x8 kh[4], kl[4];
#pragma unroll
            for (int ni = 0; ni < 4; ++ni) {
                int row = ni*16 + r16;
                int idx = row*64 + ((kk*4 + ko) ^ (row & 7)) * 8;
                kh[ni] = *reinterpret_cast<const bf16x8*>(sKh + idx);
                kl[ni] = *reinterpret_cast<const bf16x8*>(sKl + idx);
            }
#pragma unroll
            for (int mi = 0; mi < 2; ++mi)
#pragma unroll
                for (int ni = 0; ni < 4; ++ni) {
                    acc[mi][ni] = __builtin_amdgcn_mfma_f32_16x16x32_bf16(qh[mi][kk], kh[ni], acc[mi][ni], 0, 0, 0);
                    acc[mi][ni] = __builtin_amdgcn_mfma_f32_16x16x32_bf16(qh[mi][kk], kl[ni], acc[mi][ni], 0, 0, 0);
                    acc[mi][ni] = __builtin_amdgcn_mfma_f32_16x16x32_bf16(ql[mi][kk], kh[ni], acc[mi][ni], 0, 0, 0);
                }
        }

        // normalize, write attn (final, once), split P into LDS image
#pragma unroll
        for (int mi = 0; mi < 2; ++mi)
#pragma unroll
            for (int ni = 0; ni < 4; ++ni) {
                int colL = ni*16 + r16;
#pragma unroll
                for (int i = 0; i < 4; ++i) {
                    int rowL = w*32 + mi*16 + ko*4 + i;
                    float p = __expf(acc[mi][ni][i] * scale) * inv[mi][i];
                    Eb[(size_t)(i0 + rowL) * Nn + j0 + colL] = p;
                    u16 hh, ll; split_bf16(p, hh, ll);
                    int idx = img_off(rowL, colL);
                    sPh[idx] = hh; sPl[idx] = ll;
                }
            }
        __syncthreads();   // P complete (K reads also done)

#pragma unroll
        for (int kk = 0; kk < 2; ++kk) {
            bf16x8 ph[2], pl[2], vh[4], vl[4];
#pragma unroll
            for (int mi = 0; mi < 2; ++mi) {
                int row = w*32 + mi*16 + r16;
                int idx = row*64 + ((kk*4 + ko) ^ (row & 7)) * 8;
                ph[mi] = *reinterpret_cast<const bf16x8*>(sPh + idx);
                pl[mi] = *reinterpret_cast<const bf16x8*>(sPl + idx);
            }
#pragma unroll
            for (int ni = 0; ni < 4; ++ni) {
                int row = ni*16 + r16;
                int idx = row*64 + ((kk*4 + ko) ^ (row & 7)) * 8;
                vh[ni] = *reinterpret_cast<const bf16x8*>(sVh + idx);
                vl[ni] = *reinterpret_cast<const bf16x8*>(sVl + idx);
            }
#pragma unroll
            for (int mi = 0; mi < 2; ++mi)
#pragma unroll
                for (int ni = 0; ni < 4; ++ni) {
                    oacc[mi][ni] = __builtin_amdgcn_mfma_f32_16x16x32_bf16(ph[mi], vh[ni], oacc[mi][ni], 0, 0, 0);
                    oacc[mi][ni] = __builtin_amdgcn_mfma_f32_16x16x32_bf16(ph[mi], vl[ni], oacc[mi][ni], 0, 0, 0);
                    oacc[mi][ni] = __builtin_amdgcn_mfma_f32_16x16x32_bf16(pl[mi], vh[ni], oacc[mi][ni], 0, 0, 0);
                }
        }
        __syncthreads();   // PV reads done before next restage
    }

    // O epilogue: bf16 pair for proj
    const int b = bh / Hh, h = bh % Hh;
#pragma unroll
    for (int mi = 0; mi < 2; ++mi)
#pragma unroll
        for (int ni = 0; ni < 4; ++ni) {
            int d = ni*16 + r16;
#pragma unroll
            for (int i = 0; i < 4; ++i) {
                int n = i0 + w*32 + mi*16 + ko*4 + i;
                u16 hh, ll; split_bf16(oacc[mi][ni][i], hh, ll);
                size_t base = ((size_t)(b * Nn + n)) * Cc + h * Dd + d;
                Oh[base] = hh; Ol[base] = ll;
            }
        }
}

// ---------------------------------------------------------------------------
// Kernel 3: output projection via bf16x3 MFMA + bias (unchanged).
// ---------------------------------------------------------------------------
__global__ __launch_bounds__(256, 2)
void proj_mfma(const u16* __restrict__ oh, const u16* __restrict__ ol,
               const u16* __restrict__ wh, const u16* __restrict__ wl,
               const float* __restrict__ bias, float* __restrict__ out)
{
    const int m0 = blockIdx.x * 128, j0 = blockIdx.y * 128;
    f32x4 acc[4][4];
    gemm128_bf16x3(oh, ol, wh, wl, m0, j0, acc);

    const int tid = threadIdx.x;
    const int ln = tid & 63, wid = tid >> 6;
    const int wr = wid >> 1, wc = wid & 1;
#pragma unroll
    for (int mi = 0; mi < 4; ++mi) {
        int gm0 = m0 + wr*64 + mi*16 + (ln >> 4) * 4;
#pragma unroll
        for (int ni = 0; ni < 4; ++ni) {
            int col = j0 + wc*64 + ni*16 + (ln & 15);
            float bv = bias[col];
#pragma unroll
            for (int i = 0; i < 4; ++i)
                out[(size_t)(gm0 + i) * Cc + col] = acc[mi][ni][i] + bv;
        }
    }
}

extern "C" void kernel_launch(void* const* d_in, const int* in_sizes, int n_in,
                              void* d_out, int out_size, void* d_ws, size_t ws_size,
                              hipStream_t stream)
{
    const float* x      = (const float*)d_in[0];
    const float* w_qkv  = (const float*)d_in[1];
    const float* w_proj = (const float*)d_in[2];
    const float* b_proj = (const float*)d_in[3];

    float* out  = (float*)d_out;                    // [8192 x 768]
    float* attn = out + (size_t)Mm * Cc;            // [96 x 1024 x 1024]

    const size_t qkv_elems = (size_t)BHn * Nn * Dd; // 6291456
    // Q/K tile-images and V^T, bf16 hi/lo pairs (same byte footprint as r2)
    u16* Qh  = (u16*)d_ws;
    u16* Ql  = Qh  + qkv_elems;
    u16* Kh  = Ql  + qkv_elems;
    u16* Kl  = Kh  + qkv_elems;
    u16* Vth = Kl  + qkv_elems;
    u16* Vtl = Vth + qkv_elems;
    float* Oslot  = (float*)(Vtl + qkv_elems);      // Oh+Ol bf16 = Mm*Cc fp32 bytes
    float* gap    = Oslot + (size_t)Mm * Cc;        // (former rowsum slot, unused)
    u16* wph = (u16*)(gap + (size_t)BHn * Nn);
    u16* wpl = wph + (size_t)Cc * Cc;

    u16* Oh = (u16*)Oslot;
    u16* Ol = Oh + (size_t)Mm * Cc;

    // x / w_qkv splits live in the attn output region: dead until attn_fused
    // writes it, and qkv_mfma (the only consumer) completes before that.
    u16* xh  = (u16*)attn;
    u16* xl  = xh + (size_t)Mm * Cc;
    u16* wqh = xl + (size_t)Mm * Cc;
    u16* wql = wqh + (size_t)TCc * Cc;

    split_kernel<<<dim3(2048), 256, 0, stream>>>(x,      xh,  xl,  (int)((size_t)Mm * Cc / 4));
    split_kernel<<<dim3(1728), 256, 0, stream>>>(w_qkv,  wqh, wql, (int)((size_t)TCc * Cc / 4));
    split_kernel<<<dim3(576),  256, 0, stream>>>(w_proj, wph, wpl, (int)((size_t)Cc * Cc / 4));

    qkv_mfma  <<<dim3(Mm/128, TCc/128), 256, 0, stream>>>(xh, xl, wqh, wql,
                                                          Qh, Ql, Kh, Kl, Vth, Vtl);
    attn_fused<<<dim3(768), 256, 0, stream>>>(Qh, Ql, Kh, Kl, Vth, Vtl, attn, Oh, Ol);
    proj_mfma <<<dim3(Mm/128, Cc/128), 256, 0, stream>>>(Oh, Ol, wph, wpl, b_proj, out);
}